// Round 1
// baseline (590.950 us; speedup 1.0000x reference)
//
#include <hip/hip_runtime.h>

// AttnPool3D: logits = feat·w + 2*clip(mask,0,1); w = softmax_n(logits); out[b,c] = Σ_n feat*w
// Shapes fixed by setup_inputs(): B=2, C=128, N = 48*96*96 = 442368, all fp32.
//
// Single-read schedule: pass1 reads feat ONCE (453 MB, BW floor ~71 µs) computing
// per-tile {max, sum, weighted channel sums}.
// R1 change: the old pass2 was 2 blocks total -> latency-bound (~20-25 µs pulling
// 885 KB/CU of XCD-scattered S records). Now: pass2 = 64 blocks/batch computing
// partial combines (S reads spread over 128 CUs), pass3 = tiny final reduce.
// M is recomputed redundantly but bitwise-identically in pass2/pass3 (same code,
// same order) so the scheme stays deterministic — no atomics.
constexpr int C   = 128;
constexpr int N   = 48 * 96 * 96;   // 442368
constexpr int B   = 2;
constexpr int P   = 256;            // positions per block tile
constexpr int BPB = N / P;          // 1728 (exact)
constexpr int G   = 16;             // channels per thread
constexpr int NW  = 8;              // waves per pass1 block (= channel groups)
constexpr int KB  = 64;             // combine blocks per batch (pass2)
constexpr int RPB = BPB / KB;       // 27 records per combine block

// One DPP reduce step: x += dpp_move(x). old=0 so masked-off rows add 0.
template <int CTRL, int RM>
__device__ __forceinline__ float dpp_add_step(float x) {
    int y = __builtin_amdgcn_update_dpp(0, __float_as_int(x), CTRL, RM, 0xF, true);
    return x + __int_as_float(y);
}
// Full 64-lane sum; result valid in lane 63. All VALU (DPP), DS pipe stays free.
__device__ __forceinline__ float wave_sum64(float x) {
    x = dpp_add_step<0xB1, 0xF>(x);   // xor 1
    x = dpp_add_step<0x4E, 0xF>(x);   // xor 2
    x = dpp_add_step<0x141, 0xF>(x);  // row_half_mirror (xor 4)
    x = dpp_add_step<0x140, 0xF>(x);  // row_mirror (xor 8)
    x = dpp_add_step<0x142, 0xA>(x);  // row_bcast15 -> rows 1,3
    x = dpp_add_step<0x143, 0xC>(x);  // row_bcast31 -> rows 2,3
    return x;
}

// 512 threads = 8 waves. Wave w owns channels [16w,16w+16) for ALL 256 positions
// of the tile; thread t owns positions 4t..4t+3 (float4 loads: 1 KB per wave
// per load instruction — coalescing sweet spot). f4[16] = 64 VGPRs data.
__global__ __launch_bounds__(512, 4) void attn_pool_pass1(
    const float* __restrict__ feat, const float* __restrict__ mask,
    const float* __restrict__ w, float* __restrict__ Sout, float* __restrict__ ml)
{
    const int tid = threadIdx.x;
    const int wv  = tid >> 6;          // wave = channel group, 0..7
    const int t   = tid & 63;          // position-quad within tile
    const int blk = blockIdx.x;
    const int b   = blk / BPB;
    const int n0  = (blk % BPB) * P;
    const int cb  = wv * G;

    const float* fbase = feat + (size_t)b * C * N + n0 + 4 * t;

    __shared__ float4 plog[NW][64];    // per-group partial logits (8 KB)
    __shared__ float  rmax[NW];
    __shared__ float  rsum1;
    __shared__ float  SRed[NW][G];

    // Load 16 channels x 4 positions once; fold partial logit on the fly.
    float4 f[G];
    float4 pl = make_float4(0.f, 0.f, 0.f, 0.f);
#pragma unroll
    for (int c = 0; c < G; ++c) {
        f[c] = *reinterpret_cast<const float4*>(fbase + (size_t)(cb + c) * N);
        const float wc = w[cb + c];    // wave-uniform -> scalar load
        pl.x = fmaf(f[c].x, wc, pl.x);
        pl.y = fmaf(f[c].y, wc, pl.y);
        pl.z = fmaf(f[c].z, wc, pl.z);
        pl.w = fmaf(f[c].w, wc, pl.w);
    }
    if (wv == 0) {  // fold mask bias into group-0 partial (sums to full logit)
        float4 mv = *reinterpret_cast<const float4*>(mask + (size_t)b * N + n0 + 4 * t);
        pl.x += 2.f * fminf(fmaxf(mv.x, 0.f), 1.f);
        pl.y += 2.f * fminf(fmaxf(mv.y, 0.f), 1.f);
        pl.z += 2.f * fminf(fmaxf(mv.z, 0.f), 1.f);
        pl.w += 2.f * fminf(fmaxf(mv.w, 0.f), 1.f);
    }
    plog[wv][t] = pl;
    __syncthreads();

    // full logits for this thread's 4 positions = sum of the 8 group partials
    float4 lg = plog[0][t];
#pragma unroll
    for (int g = 1; g < NW; ++g) {
        float4 q = plog[g][t];
        lg.x += q.x; lg.y += q.y; lg.z += q.z; lg.w += q.w;
    }

    // tile max (duplicated across waves; max unaffected)
    float m = fmaxf(fmaxf(lg.x, lg.y), fmaxf(lg.z, lg.w));
#pragma unroll
    for (int off = 32; off; off >>= 1) m = fmaxf(m, __shfl_xor(m, off, 64));
    if (t == 0) rmax[wv] = m;
    __syncthreads();
    m = fmaxf(fmaxf(fmaxf(rmax[0], rmax[1]), fmaxf(rmax[2], rmax[3])),
              fmaxf(fmaxf(rmax[4], rmax[5]), fmaxf(rmax[6], rmax[7])));

    const float p0 = __expf(lg.x - m), p1 = __expf(lg.y - m);
    const float p2 = __expf(lg.z - m), p3 = __expf(lg.w - m);

    // tile sum of p: wave 0 covers all 256 positions exactly once
    if (wv == 0) {
        float l = ((p0 + p1) + (p2 + p3));
#pragma unroll
        for (int off = 32; off; off >>= 1) l += __shfl_xor(l, off, 64);
        if (t == 0) rsum1 = l;
    }

    // S_c = sum over the wave's 256 positions of f*p  (16 DPP chains/thread)
#pragma unroll
    for (int c = 0; c < G; ++c) {
        float s = f[c].x * p0;
        s = fmaf(f[c].y, p1, s);
        s = fmaf(f[c].z, p2, s);
        s = fmaf(f[c].w, p3, s);
        s = wave_sum64(s);
        if (t == 63) SRed[wv][c] = s;
    }
    __syncthreads();

    if (tid < C) {
        Sout[(size_t)blk * C + tid] = SRed[tid >> 4][tid & 15];  // contiguous record
    } else if (tid == C) {
        ml[2 * blk]     = m;
        ml[2 * blk + 1] = rsum1;
    }
}

// Pass2: KB blocks per batch. Each block (a) recomputes the global max M from the
// compact ml array (13.8 KB, L2-hot; identical thread-order in every block so M is
// bitwise-identical), (b) combines its RPB=27 S-records into a partial channel
// vector part[b][k][c]. 128 blocks spread the 1.77 MB of S reads across 128 CUs —
// the old single-block-per-batch version was remote-L2-latency-bound (~20 µs).
__global__ __launch_bounds__(256) void attn_pool_pass2(
    const float* __restrict__ S, const float* __restrict__ ml,
    float* __restrict__ part)
{
    const int b    = blockIdx.x / KB;
    const int k    = blockIdx.x % KB;
    const int tid  = threadIdx.x;
    const int lane = tid & 63;
    const int wv   = tid >> 6;          // 0..3
    const float2* mlb = (const float2*)(ml + (size_t)b * BPB * 2);
    const float*  Sb  = S + (size_t)b * BPB * C;

    __shared__ float red[4];
    __shared__ float half1[C];

    // global max M over tile maxima (deterministic, same in every block of batch b)
    float m = -3.4e38f;
    for (int i = tid; i < BPB; i += 256) m = fmaxf(m, mlb[i].x);
#pragma unroll
    for (int off = 32; off; off >>= 1) m = fmaxf(m, __shfl_xor(m, off, 64));
    if (lane == 0) red[wv] = m;
    __syncthreads();
    const float M = fmaxf(fmaxf(red[0], red[1]), fmaxf(red[2], red[3]));

    // partial combine over this block's records (coalesced: lanes -> consecutive c)
    const int c = tid & (C - 1);
    const int h = tid >> 7;             // 0,1: split records between thread halves
    const int i0 = k * RPB;
    float acc = 0.f;
    for (int i = i0 + h; i < i0 + RPB; i += 2)
        acc = fmaf(Sb[(size_t)i * C + c], __expf(mlb[i].x - M), acc);
    if (h) half1[c] = acc;
    __syncthreads();
    if (!h) part[((size_t)b * KB + k) * C + c] = acc + half1[c];
}

// Pass3: one small block per batch. Recompute M (identical order -> identical
// value as pass2), compute Z, sum the KB partials per channel, divide by Z.
__global__ __launch_bounds__(256) void attn_pool_pass3(
    const float* __restrict__ part, const float* __restrict__ ml,
    float* __restrict__ out)
{
    const int b    = blockIdx.x;
    const int tid  = threadIdx.x;
    const int lane = tid & 63;
    const int wv   = tid >> 6;
    const float2* mlb = (const float2*)(ml + (size_t)b * BPB * 2);

    __shared__ float redA[4], redB[4];
    __shared__ float half1[C];

    float m = -3.4e38f;
    for (int i = tid; i < BPB; i += 256) m = fmaxf(m, mlb[i].x);
#pragma unroll
    for (int off = 32; off; off >>= 1) m = fmaxf(m, __shfl_xor(m, off, 64));
    if (lane == 0) redA[wv] = m;
    __syncthreads();
    const float M = fmaxf(fmaxf(redA[0], redA[1]), fmaxf(redA[2], redA[3]));

    // Z = sum_i l_i * e^{m_i - M}
    float z = 0.f;
    for (int i = tid; i < BPB; i += 256) {
        float2 v = mlb[i];
        z = fmaf(v.y, __expf(v.x - M), z);
    }
#pragma unroll
    for (int off = 32; off; off >>= 1) z += __shfl_xor(z, off, 64);
    if (lane == 0) redB[wv] = z;
    __syncthreads();
    const float Z = redB[0] + redB[1] + redB[2] + redB[3];

    const int c = tid & (C - 1);
    const int h = tid >> 7;
    float tot = 0.f;
    for (int k = h; k < KB; k += 2)
        tot += part[((size_t)b * KB + k) * C + c];
    if (h) half1[c] = tot;
    __syncthreads();
    if (!h) out[b * C + c] = (tot + half1[c]) / Z;
}

extern "C" void kernel_launch(void* const* d_in, const int* in_sizes, int n_in,
                              void* d_out, int out_size, void* d_ws, size_t ws_size,
                              hipStream_t stream)
{
    const float* feat = (const float*)d_in[0];
    const float* mask = (const float*)d_in[1];
    const float* w    = (const float*)d_in[2];

    float* Sout = (float*)d_ws;                         // B*BPB*C floats = 1.77 MB
    float* ml   = Sout + (size_t)B * BPB * C;           // B*BPB*2 floats = 27.6 KB
    float* part = ml + (size_t)B * BPB * 2;             // B*KB*C floats  = 64 KB

    attn_pool_pass1<<<B * BPB, 512, 0, stream>>>(feat, mask, w, Sout, ml);
    attn_pool_pass2<<<B * KB, 256, 0, stream>>>(Sout, ml, part);
    attn_pool_pass3<<<B, 256, 0, stream>>>(part, ml, (float*)d_out);
}